// Round 11
// baseline (79.687 us; speedup 1.0000x reference)
//
#include <hip/hip_runtime.h>
#include <hip/hip_bf16.h>

#define DD 128
#define NEGS 0.01f

typedef float  f32x4 __attribute__((ext_vector_type(4)));
typedef float  f32x2 __attribute__((ext_vector_type(2)));
typedef __bf16 bf16x8 __attribute__((ext_vector_type(8)));
typedef unsigned short us8 __attribute__((ext_vector_type(8)));

__device__ __forceinline__ unsigned short f2bf(float f) {
    unsigned int u = __builtin_bit_cast(unsigned int, f);
    u += 0x7FFFu + ((u >> 16) & 1u);          // RNE (no NaN inputs here)
    return (unsigned short)(u >> 16);
}
__device__ __forceinline__ float sb2f(unsigned int u, int byte) {
    return (float)(int)(signed char)((u >> (byte * 8)) & 0xffu);
}

// ---------- fused GEMM + logits + row-quant + segment-starts ---------------
// Blocks [0,NB): GEMM, 256 thr = 4 waves x 32 rows = 128 rows/block.
// h/W staged in LDS as bf16 (slot-swizzled, ds_read_b128 ~2-way = free).
// Epilogue: ll/lr logits + per-row absmax; z8 stored SPLIT BY COLUMN HALF:
// z8[half][node][64] so each half is a contiguous 3.2 MB region (fits a
// 4 MB per-XCD L2). lls[row] = {ll, rowmax/127}.
// Blocks [NB,NB+SB): start[n] = lower_bound(dst, n).
__global__ __launch_bounds__(256)
void k_gemm(const float* __restrict__ h, const float* __restrict__ W,
            const float* __restrict__ attn, const int* __restrict__ dst,
            int E, int N, int NB,
            signed char* __restrict__ z8, float2* __restrict__ lls,
            float* __restrict__ lrv, int* __restrict__ start)
{
    if (blockIdx.x >= NB) {               // ---- segment starts part ----
        int n = (blockIdx.x - NB) * 256 + threadIdx.x;
        if (n > N) return;
        int lo = 0, hi = E;
        while (lo < hi) {
            int mid = (lo + hi) >> 1;
            if (dst[mid] < n) lo = mid + 1; else hi = mid;
        }
        start[n] = lo;
        return;
    }

    __shared__ unsigned short hs[128 * DD];   // 32 KB, swizzled bf16
    __shared__ unsigned short ws[DD * DD];    // 32 KB, swizzled bf16
    const int tid  = threadIdx.x;
    const int row0 = blockIdx.x * 128;

    {   // stage W (fp32 -> bf16, swizzled)
        const int r = tid >> 4, c = tid & 15;
#pragma unroll
        for (int p = 0; p < DD; p += 16) {
            const int rr = p + r;
            const float* pw = W + (size_t)rr * DD + c * 8;
            float4 a = *(const float4*)pw, b = *(const float4*)(pw + 4);
            us8 v = { f2bf(a.x), f2bf(a.y), f2bf(a.z), f2bf(a.w),
                      f2bf(b.x), f2bf(b.y), f2bf(b.z), f2bf(b.w) };
            *(us8*)(ws + rr * DD + ((c ^ (rr & 15)) * 8)) = v;
        }
    }
    {   // stage h rows [row0, row0+128) (clamped)
        const int r = tid >> 4, c = tid & 15;
#pragma unroll
        for (int p = 0; p < 128; p += 16) {
            const int rr = p + r;
            int gr = row0 + rr; if (gr > N - 1) gr = N - 1;
            const float* ph = h + (size_t)gr * DD + c * 8;
            float4 a = *(const float4*)ph, b = *(const float4*)(ph + 4);
            us8 v = { f2bf(a.x), f2bf(a.y), f2bf(a.z), f2bf(a.w),
                      f2bf(b.x), f2bf(b.y), f2bf(b.z), f2bf(b.w) };
            *(us8*)(hs + rr * DD + ((c ^ (rr & 15)) * 8)) = v;
        }
    }
    __syncthreads();

    const int w    = tid >> 6;
    const int lane = tid & 63;
    const int hl   = lane & 15;
    const int g    = lane >> 4;

    f32x4 acc[2][8];
#pragma unroll
    for (int rt = 0; rt < 2; ++rt)
#pragma unroll
        for (int jt = 0; jt < 8; ++jt) acc[rt][jt] = f32x4{0.f, 0.f, 0.f, 0.f};

#pragma unroll
    for (int kk = 0; kk < DD; kk += 32) {
        const int cb = (kk >> 3) + g;
        const int ra0 = w * 32 + hl;
        const int ra1 = ra0 + 16;
        bf16x8 a0 = *(const bf16x8*)(hs + ra0 * DD + ((cb ^ (ra0 & 15)) * 8));
        bf16x8 a1 = *(const bf16x8*)(hs + ra1 * DD + ((cb ^ (ra1 & 15)) * 8));
#pragma unroll
        for (int jt = 0; jt < 8; ++jt) {
            const int rb = jt * 16 + hl;
            bf16x8 b = *(const bf16x8*)(ws + rb * DD + ((cb ^ (rb & 15)) * 8));
            acc[0][jt] = __builtin_amdgcn_mfma_f32_16x16x32_bf16(a0, b, acc[0][jt], 0, 0, 0);
            acc[1][jt] = __builtin_amdgcn_mfma_f32_16x16x32_bf16(a1, b, acc[1][jt], 0, 0, 0);
        }
    }

    // epilogue: logits + row absmax + int8 quantize (split layout)
    float aLc[8], aRc[8];
#pragma unroll
    for (int jt = 0; jt < 8; ++jt) {
        aLc[jt] = attn[jt * 16 + hl];
        aRc[jt] = attn[DD + jt * 16 + hl];
    }
    const size_t halfStride = (size_t)N * 64;
#pragma unroll
    for (int rt = 0; rt < 2; ++rt) {
#pragma unroll
        for (int reg = 0; reg < 4; ++reg) {
            const int row = row0 + w * 32 + rt * 16 + g * 4 + reg;
            float pl = 0.f, pr = 0.f, am = 0.f;
#pragma unroll
            for (int jt = 0; jt < 8; ++jt) {
                float v = acc[rt][jt][reg];
                pl = fmaf(v, aLc[jt], pl);
                pr = fmaf(v, aRc[jt], pr);
                am = fmaxf(am, fabsf(v));
            }
#pragma unroll
            for (int o = 8; o >= 1; o >>= 1) {   // reduce across 16 cols
                pl += __shfl_xor(pl, o);
                pr += __shfl_xor(pr, o);
                am = fmaxf(am, __shfl_xor(am, o));
            }
            if (row < N) {
                const float inv_s = (am > 0.f) ? 127.f / am : 0.f;
                if (hl == 0) {
                    lls[row] = make_float2(pl, am * (1.f / 127.f));
                    lrv[row] = pr;
                }
#pragma unroll
                for (int jt = 0; jt < 8; ++jt)
                    z8[(size_t)(jt >> 2) * halfStride + (size_t)row * 64
                       + (jt & 3) * 16 + hl] =
                        (signed char)__float2int_rn(acc[rt][jt][reg] * inv_s);
            }
        }
    }
}

// ------- edge weights: pw[j] = {w, w*s_src}, w = exp(leaky(ll_s + lr_d)) ---
// lls is 400 KB (L2-hot everywhere); lr[dst] is near-sequential (dst sorted).
// No max-subtraction: logits O(10), exp fp32-safe, softmax shift-invariant.
__global__ __launch_bounds__(256)
void k_ew(const int* __restrict__ src, const int* __restrict__ dst,
          const float2* __restrict__ lls, const float* __restrict__ lrv,
          f32x2* __restrict__ pw, int E)
{
    int j = blockIdx.x * 256 + threadIdx.x;
    if (j >= E) return;
    float2 p = lls[src[j]];
    float v = p.x + lrv[dst[j]];
    float e = (v >= 0.f) ? v : NEGS * v;
    float w = __expf(e);
    f32x2 o = {w, w * p.y};
    __builtin_nontemporal_store(o, pw + j);
}

// ---------------- output, column-halved: z half fits per-XCD L2 -----------
// Grid = 2*G2; blocks [0,G2) do half 0, [G2,2*G2) half 1. Dispatch is
// ~in-order, so resident blocks share one 3.2 MB z-half -> L2 hits.
// wave = node; quarter q handles edges base+q, base+q+4; 16 lanes x 4 B
// cover the 64 B half-row (exactly one line per edge).
// src/pw/out are non-temporal: the z-half owns L2.
__global__ __launch_bounds__(256)
void k_out(const signed char* __restrict__ z8, const int* __restrict__ src,
           const f32x2* __restrict__ pw, const int* __restrict__ start,
           float* __restrict__ out, int N, int G2)
{
    const int half = (blockIdx.x >= G2) ? 1 : 0;
    const int b    = blockIdx.x - half * G2;
    int wid  = (b * 256 + threadIdx.x) >> 6;
    int lane = threadIdx.x & 63;
    if (wid >= N) return;
    const int s0 = start[wid], s1 = start[wid + 1];
    const int q = lane >> 4;      // quarter 0..3
    const int c = lane & 15;      // byte block: 4 cols per lane
    const signed char* zh = z8 + (size_t)half * N * 64;

    float a0 = 0.f, a1 = 0.f, a2 = 0.f, a3 = 0.f, ssum = 0.f;
    const int last = s1 - 1;

    for (int base = s0; base < s1; base += 8) {
        int t0 = base + q;
        int t1 = t0 + 4;
        int tc0 = (t0 <= last) ? t0 : last;
        int tc1 = (t1 <= last) ? t1 : last;
        int sj0 = __builtin_nontemporal_load(src + tc0);
        int sj1 = __builtin_nontemporal_load(src + tc1);
        f32x2 p0 = __builtin_nontemporal_load(pw + tc0);
        f32x2 p1 = __builtin_nontemporal_load(pw + tc1);
        float w0 = p0[0], u0 = p0[1];
        float w1 = p1[0], u1 = p1[1];
        if (t0 > last) { w0 = 0.f; u0 = 0.f; }
        if (t1 > last) { w1 = 0.f; u1 = 0.f; }
        unsigned int z0 = *(const unsigned int*)(zh + (size_t)sj0 * 64 + c * 4);
        unsigned int z1 = *(const unsigned int*)(zh + (size_t)sj1 * 64 + c * 4);
        ssum += w0 + w1;
        a0 = fmaf(u0, sb2f(z0, 0), fmaf(u1, sb2f(z1, 0), a0));
        a1 = fmaf(u0, sb2f(z0, 1), fmaf(u1, sb2f(z1, 1), a1));
        a2 = fmaf(u0, sb2f(z0, 2), fmaf(u1, sb2f(z1, 2), a2));
        a3 = fmaf(u0, sb2f(z0, 3), fmaf(u1, sb2f(z1, 3), a3));
    }
    // combine the 4 quarters (lanes {l, l^16, l^32, l^48} share a col block)
    a0 += __shfl_xor(a0, 16);  a0 += __shfl_xor(a0, 32);
    a1 += __shfl_xor(a1, 16);  a1 += __shfl_xor(a1, 32);
    a2 += __shfl_xor(a2, 16);  a2 += __shfl_xor(a2, 32);
    a3 += __shfl_xor(a3, 16);  a3 += __shfl_xor(a3, 32);
    ssum += __shfl_xor(ssum, 16);
    ssum += __shfl_xor(ssum, 32);
    float inv = (s1 > s0) ? 1.0f / ssum : 0.f;   // empty segment -> zeros

    if (q == 0) {
        f32x4 o = {a0 * inv, a1 * inv, a2 * inv, a3 * inv};
        __builtin_nontemporal_store(o,
            (f32x4*)(out + (size_t)wid * DD + half * 64 + c * 4));
    }
}

extern "C" void kernel_launch(void* const* d_in, const int* in_sizes, int n_in,
                              void* d_out, int out_size, void* d_ws, size_t ws_size,
                              hipStream_t stream) {
    const float* h    = (const float*)d_in[0];
    const int*   src  = (const int*)d_in[1];
    const int*   dst  = (const int*)d_in[2];
    const float* W    = (const float*)d_in[3];
    const float* attn = (const float*)d_in[4];
    const int N = in_sizes[0] / DD;
    const int E = in_sizes[1];
    float* out = (float*)d_out;

    // workspace layout
    signed char* z8 = (signed char*)d_ws;               // 2 x N*64 int8 (6.4 MB)
    float2* lls = (float2*)(z8 + (size_t)N * DD);       // N float2 {ll, s}
    float* lrv  = (float*)(lls + N);                    // N
    f32x2* pw   = (f32x2*)(lrv + N);                    // E float2 {w, w*s} (6.4 MB)
    int* start  = (int*)(pw + E);                       // N+1

    const int NB = (N + 127) / 128;          // gemm blocks
    const int SB = (N + 1 + 255) / 256;      // starts blocks
    const int G2 = (N + 3) / 4;              // k_out blocks per half

    k_gemm<<<NB + SB, 256, 0, stream>>>(h, W, attn, dst, E, N, NB, z8, lls, lrv, start);
    k_ew<<<(E + 255) / 256, 256, 0, stream>>>(src, dst, lls, lrv, pw, E);
    k_out<<<2 * G2, 256, 0, stream>>>(z8, src, pw, start, out, N, G2);
}

// Round 12
// 49.687 us; speedup vs baseline: 1.6038x; 1.6038x over previous
//
#include <hip/hip_runtime.h>
#include <hip/hip_bf16.h>

#define DD 128
#define NEGS 0.01f

typedef float  f32x4 __attribute__((ext_vector_type(4)));
typedef __bf16 bf16x8 __attribute__((ext_vector_type(8)));
typedef unsigned short us8 __attribute__((ext_vector_type(8)));

__device__ __forceinline__ unsigned short f2bf(float f) {
    unsigned int u = __builtin_bit_cast(unsigned int, f);
    u += 0x7FFFu + ((u >> 16) & 1u);          // RNE (no NaN inputs here)
    return (unsigned short)(u >> 16);
}
__device__ __forceinline__ float sb2f(unsigned int u, int byte) {
    return (float)(int)(signed char)((u >> (byte * 8)) & 0xffu);
}

// ---------- fused GEMM + logits + row-quant + segment-starts ---------------
// (identical to round 10 — best known)
__global__ __launch_bounds__(256)
void k_gemm(const float* __restrict__ h, const float* __restrict__ W,
            const float* __restrict__ attn, const int* __restrict__ dst,
            int E, int N, int NB,
            signed char* __restrict__ z8, float2* __restrict__ lls,
            float* __restrict__ lrv, int* __restrict__ start)
{
    if (blockIdx.x >= NB) {               // ---- segment starts part ----
        int n = (blockIdx.x - NB) * 256 + threadIdx.x;
        if (n > N) return;
        int lo = 0, hi = E;
        while (lo < hi) {
            int mid = (lo + hi) >> 1;
            if (dst[mid] < n) lo = mid + 1; else hi = mid;
        }
        start[n] = lo;
        return;
    }

    __shared__ unsigned short hs[128 * DD];   // 32 KB, swizzled bf16
    __shared__ unsigned short ws[DD * DD];    // 32 KB, swizzled bf16
    const int tid  = threadIdx.x;
    const int row0 = blockIdx.x * 128;

    {   // stage W (fp32 -> bf16, swizzled)
        const int r = tid >> 4, c = tid & 15;
#pragma unroll
        for (int p = 0; p < DD; p += 16) {
            const int rr = p + r;
            const float* pw = W + (size_t)rr * DD + c * 8;
            float4 a = *(const float4*)pw, b = *(const float4*)(pw + 4);
            us8 v = { f2bf(a.x), f2bf(a.y), f2bf(a.z), f2bf(a.w),
                      f2bf(b.x), f2bf(b.y), f2bf(b.z), f2bf(b.w) };
            *(us8*)(ws + rr * DD + ((c ^ (rr & 15)) * 8)) = v;
        }
    }
    {   // stage h rows [row0, row0+128) (clamped)
        const int r = tid >> 4, c = tid & 15;
#pragma unroll
        for (int p = 0; p < 128; p += 16) {
            const int rr = p + r;
            int gr = row0 + rr; if (gr > N - 1) gr = N - 1;
            const float* ph = h + (size_t)gr * DD + c * 8;
            float4 a = *(const float4*)ph, b = *(const float4*)(ph + 4);
            us8 v = { f2bf(a.x), f2bf(a.y), f2bf(a.z), f2bf(a.w),
                      f2bf(b.x), f2bf(b.y), f2bf(b.z), f2bf(b.w) };
            *(us8*)(hs + rr * DD + ((c ^ (rr & 15)) * 8)) = v;
        }
    }
    __syncthreads();

    const int w    = tid >> 6;
    const int lane = tid & 63;
    const int hl   = lane & 15;
    const int g    = lane >> 4;

    f32x4 acc[2][8];
#pragma unroll
    for (int rt = 0; rt < 2; ++rt)
#pragma unroll
        for (int jt = 0; jt < 8; ++jt) acc[rt][jt] = f32x4{0.f, 0.f, 0.f, 0.f};

#pragma unroll
    for (int kk = 0; kk < DD; kk += 32) {
        const int cb = (kk >> 3) + g;
        const int ra0 = w * 32 + hl;
        const int ra1 = ra0 + 16;
        bf16x8 a0 = *(const bf16x8*)(hs + ra0 * DD + ((cb ^ (ra0 & 15)) * 8));
        bf16x8 a1 = *(const bf16x8*)(hs + ra1 * DD + ((cb ^ (ra1 & 15)) * 8));
#pragma unroll
        for (int jt = 0; jt < 8; ++jt) {
            const int rb = jt * 16 + hl;
            bf16x8 b = *(const bf16x8*)(ws + rb * DD + ((cb ^ (rb & 15)) * 8));
            acc[0][jt] = __builtin_amdgcn_mfma_f32_16x16x32_bf16(a0, b, acc[0][jt], 0, 0, 0);
            acc[1][jt] = __builtin_amdgcn_mfma_f32_16x16x32_bf16(a1, b, acc[1][jt], 0, 0, 0);
        }
    }

    // epilogue: logits + row absmax + int8 quantize
    float aLc[8], aRc[8];
#pragma unroll
    for (int jt = 0; jt < 8; ++jt) {
        aLc[jt] = attn[jt * 16 + hl];
        aRc[jt] = attn[DD + jt * 16 + hl];
    }
#pragma unroll
    for (int rt = 0; rt < 2; ++rt) {
#pragma unroll
        for (int reg = 0; reg < 4; ++reg) {
            const int row = row0 + w * 32 + rt * 16 + g * 4 + reg;
            float pl = 0.f, pr = 0.f, am = 0.f;
#pragma unroll
            for (int jt = 0; jt < 8; ++jt) {
                float v = acc[rt][jt][reg];
                pl = fmaf(v, aLc[jt], pl);
                pr = fmaf(v, aRc[jt], pr);
                am = fmaxf(am, fabsf(v));
            }
#pragma unroll
            for (int o = 8; o >= 1; o >>= 1) {   // reduce across 16 cols
                pl += __shfl_xor(pl, o);
                pr += __shfl_xor(pr, o);
                am = fmaxf(am, __shfl_xor(am, o));
            }
            if (row < N) {
                const float inv_s = (am > 0.f) ? 127.f / am : 0.f;
                if (hl == 0) {
                    lls[row] = make_float2(pl, am * (1.f / 127.f));
                    lrv[row] = pr;
                }
                signed char* zr = z8 + (size_t)row * DD;
#pragma unroll
                for (int jt = 0; jt < 8; ++jt)
                    zr[jt * 16 + hl] =
                        (signed char)__float2int_rn(acc[rt][jt][reg] * inv_s);
            }
        }
    }
}

// ---------------- fused output: int8 gather, 16 edges/iter in flight -------
// wave = node; quarter q owns edges base+q, +4, +8, +12 (4 independent
// src->z gather chains per lane). Clamp-free fast path; masked 8-edge tail
// (round-10 form). lls[src] = {ll, s}: one 8B load = logit + dequant scale.
// No max-subtraction (logits O(10), exp fp32-safe, softmax shift-invariant).
__global__ __launch_bounds__(256)
void k_out(const signed char* __restrict__ z8, const int* __restrict__ src,
           const float2* __restrict__ lls, const float* __restrict__ lrv,
           const int* __restrict__ start, float* __restrict__ out, int N)
{
    int wid  = (blockIdx.x * 256 + threadIdx.x) >> 6;
    int lane = threadIdx.x & 63;
    if (wid >= N) return;
    const int s0 = start[wid], s1 = start[wid + 1];
    const int q = lane >> 4;      // quarter 0..3
    const int c = lane & 15;      // byte block: cols 8c .. 8c+7
    const float lrn = lrv[wid];

    float acc[8];
#pragma unroll
    for (int k = 0; k < 8; ++k) acc[k] = 0.f;
    float ssum = 0.f;
    const int last = s1 - 1;

    int base = s0;
    // fast path: 16 edges, no masking (all indices < s1)
    for (; base + 16 <= s1; base += 16) {
        int t0 = base + q, t1 = t0 + 4, t2 = t0 + 8, t3 = t0 + 12;
        int sj0 = __builtin_nontemporal_load(src + t0);
        int sj1 = __builtin_nontemporal_load(src + t1);
        int sj2 = __builtin_nontemporal_load(src + t2);
        int sj3 = __builtin_nontemporal_load(src + t3);
        uint2 z0 = *(const uint2*)(z8 + (size_t)sj0 * DD + c * 8);
        uint2 z1 = *(const uint2*)(z8 + (size_t)sj1 * DD + c * 8);
        uint2 z2 = *(const uint2*)(z8 + (size_t)sj2 * DD + c * 8);
        uint2 z3 = *(const uint2*)(z8 + (size_t)sj3 * DD + c * 8);
        float2 p0 = lls[sj0];
        float2 p1 = lls[sj1];
        float2 p2 = lls[sj2];
        float2 p3 = lls[sj3];
        float v0 = p0.x + lrn;  v0 = (v0 >= 0.f) ? v0 : NEGS * v0;
        float v1 = p1.x + lrn;  v1 = (v1 >= 0.f) ? v1 : NEGS * v1;
        float v2 = p2.x + lrn;  v2 = (v2 >= 0.f) ? v2 : NEGS * v2;
        float v3 = p3.x + lrn;  v3 = (v3 >= 0.f) ? v3 : NEGS * v3;
        float w0 = __expf(v0), w1 = __expf(v1);
        float w2 = __expf(v2), w3 = __expf(v3);
        ssum += (w0 + w1) + (w2 + w3);
        float u0 = w0 * p0.y, u1 = w1 * p1.y;
        float u2 = w2 * p2.y, u3 = w3 * p3.y;
#pragma unroll
        for (int k = 0; k < 4; ++k) {
            acc[k]     = fmaf(u0, sb2f(z0.x, k), fmaf(u1, sb2f(z1.x, k), acc[k]));
            acc[k]     = fmaf(u2, sb2f(z2.x, k), fmaf(u3, sb2f(z3.x, k), acc[k]));
            acc[k + 4] = fmaf(u0, sb2f(z0.y, k), fmaf(u1, sb2f(z1.y, k), acc[k + 4]));
            acc[k + 4] = fmaf(u2, sb2f(z2.y, k), fmaf(u3, sb2f(z3.y, k), acc[k + 4]));
        }
    }
    // masked tail: 8 edges/iter (round-10 form)
    for (; base < s1; base += 8) {
        int t0 = base + q;
        int t1 = t0 + 4;
        int tc0 = (t0 <= last) ? t0 : last;
        int tc1 = (t1 <= last) ? t1 : last;
        int sj0 = __builtin_nontemporal_load(src + tc0);
        int sj1 = __builtin_nontemporal_load(src + tc1);
        float2 p0 = lls[sj0];
        float2 p1 = lls[sj1];
        float v0 = p0.x + lrn;  v0 = (v0 >= 0.f) ? v0 : NEGS * v0;
        float v1 = p1.x + lrn;  v1 = (v1 >= 0.f) ? v1 : NEGS * v1;
        float w0 = __expf(v0); if (t0 > last) w0 = 0.f;
        float w1 = __expf(v1); if (t1 > last) w1 = 0.f;
        uint2 z0 = *(const uint2*)(z8 + (size_t)sj0 * DD + c * 8);
        uint2 z1 = *(const uint2*)(z8 + (size_t)sj1 * DD + c * 8);
        ssum += w0 + w1;
        float u0 = w0 * p0.y;
        float u1 = w1 * p1.y;
#pragma unroll
        for (int k = 0; k < 4; ++k) {
            acc[k]     = fmaf(u0, sb2f(z0.x, k), fmaf(u1, sb2f(z1.x, k), acc[k]));
            acc[k + 4] = fmaf(u0, sb2f(z0.y, k), fmaf(u1, sb2f(z1.y, k), acc[k + 4]));
        }
    }
    // combine the 4 quarters (lanes {l, l^16, l^32, l^48} share a col block)
#pragma unroll
    for (int k = 0; k < 8; ++k) {
        acc[k] += __shfl_xor(acc[k], 16);
        acc[k] += __shfl_xor(acc[k], 32);
    }
    ssum += __shfl_xor(ssum, 16);
    ssum += __shfl_xor(ssum, 32);
    float inv = (s1 > s0) ? 1.0f / ssum : 0.f;   // empty segment -> zeros

    float* orow = out + (size_t)wid * DD + c * 8;
    if (q == 0) {
        f32x4 o = {acc[0]*inv, acc[1]*inv, acc[2]*inv, acc[3]*inv};
        __builtin_nontemporal_store(o, (f32x4*)orow);
    } else if (q == 1) {
        f32x4 o = {acc[4]*inv, acc[5]*inv, acc[6]*inv, acc[7]*inv};
        __builtin_nontemporal_store(o, ((f32x4*)orow) + 1);
    }
}

extern "C" void kernel_launch(void* const* d_in, const int* in_sizes, int n_in,
                              void* d_out, int out_size, void* d_ws, size_t ws_size,
                              hipStream_t stream) {
    const float* h    = (const float*)d_in[0];
    const int*   src  = (const int*)d_in[1];
    const int*   dst  = (const int*)d_in[2];
    const float* W    = (const float*)d_in[3];
    const float* attn = (const float*)d_in[4];
    const int N = in_sizes[0] / DD;
    const int E = in_sizes[1];
    float* out = (float*)d_out;

    // workspace layout (z8 6.4 MB, lls 400 KB, lrv 200 KB, start)
    signed char* z8 = (signed char*)d_ws;               // N*128 int8
    float2* lls = (float2*)(z8 + (size_t)N * DD);       // N float2 {ll, s}
    float* lrv  = (float*)(lls + N);                    // N
    int* start  = (int*)(lrv + N);                      // N+1

    const int NB = (N + 127) / 128;          // gemm blocks
    const int SB = (N + 1 + 255) / 256;      // starts blocks

    k_gemm<<<NB + SB, 256, 0, stream>>>(h, W, attn, dst, E, N, NB, z8, lls, lrv, start);
    k_out<<<(N + 3) / 4, 256, 0, stream>>>(z8, src, lls, lrv, start, out, N);
}